// Round 1
// baseline (216.374 us; speedup 1.0000x reference)
//
#include <hip/hip_runtime.h>

#define B_ 4
#define T_ 1024
#define C_ 1024
#define H_ 16
#define HD_ 64

typedef short bf16x8 __attribute__((ext_vector_type(8)));
typedef float f32x4 __attribute__((ext_vector_type(4)));

__device__ __forceinline__ ushort f2bf(float f) {
    union { float f; unsigned u; } v; v.f = f;
    unsigned u = v.u;
    unsigned r = (u + 0x7fffu + ((u >> 16) & 1u)) >> 16;
    return (ushort)r;
}

__device__ __forceinline__ f32x4 mfma16(bf16x8 a, bf16x8 b, f32x4 c) {
    return __builtin_amdgcn_mfma_f32_16x16x32_bf16(a, b, c, 0, 0, 0);
}

// Read a 16B MFMA fragment from a [rows][64] ushort LDS tile (128B rows),
// XOR-swizzled: byte ^= (row&7)<<4. Must match the staging-side swizzle.
__device__ __forceinline__ bf16x8 lds_frag(const ushort* base, int row, int byteoff) {
    int addr = (row * 128 + byteoff) ^ ((row & 7) << 4);
    uint4 u = *(const uint4*)((const char*)base + addr);
    return __builtin_bit_cast(bf16x8, u);
}

// Stage a 64x64 ushort tile (global rows of `ld` elems) into swizzled LDS.
// 256 threads, 2 chunks of 16B each.
__device__ __forceinline__ void stage_tile(ushort* sdst, const ushort* gsrc, int ld, int tid) {
#pragma unroll
    for (int it = 0; it < 2; ++it) {
        int c = tid + it * 256;          // chunk 0..511
        int row = c >> 3, off = c & 7;   // 8 chunks per 128B row
        uint4 v = *(const uint4*)(gsrc + (size_t)row * ld + off * 8);
        int addr = (c * 16) ^ ((row & 7) << 4);
        *(uint4*)((char*)sdst + addr) = v;
    }
}

__global__ void cast_bf16(const float* __restrict__ in, ushort* __restrict__ out, int n) {
    int i = (blockIdx.x * 256 + threadIdx.x) * 4;
    if (i >= n) return;
    float4 v = *(const float4*)(in + i);
    ushort4 o = make_ushort4(f2bf(v.x), f2bf(v.y), f2bf(v.z), f2bf(v.w));
    *(ushort4*)(out + i) = o;
}

// ---------------------------------------------------------------------------
// GEMM1: qkv = x @ W_qkv^T  (bf16 MFMA, fp32 acc), fused RoPE + norms + scatter
// Tile: 64(M) x 64(N), BK=64. 4 waves, each 16 rows x 64 cols.
// N-tile == exactly one head's 64 dims of one of q/k/v.
// ---------------------------------------------------------------------------
__global__ __launch_bounds__(256) void gemm_qkv(
    const ushort* __restrict__ Xb, const ushort* __restrict__ Wb,
    const float* __restrict__ hyp,
    ushort* __restrict__ Qo, ushort* __restrict__ Ko, ushort* __restrict__ Vo,
    float* __restrict__ q0g, float* __restrict__ k0g)
{
    __shared__ ushort As[64 * 64];
    __shared__ ushort Bs[64 * 64];
    const int tid = threadIdx.x, lane = tid & 63, wv = tid >> 6;
    const int m0 = blockIdx.x * 64, n0 = blockIdx.y * 64;

    f32x4 acc[4] = {};
    for (int kt = 0; kt < C_ / 64; ++kt) {
        stage_tile(As, Xb + (size_t)m0 * C_ + kt * 64, C_, tid);
        stage_tile(Bs, Wb + (size_t)n0 * C_ + kt * 64, C_, tid);
        __syncthreads();
#pragma unroll
        for (int ks = 0; ks < 2; ++ks) {
            bf16x8 a = lds_frag(As, wv * 16 + (lane & 15), ks * 64 + ((lane >> 4) << 4));
#pragma unroll
            for (int cf = 0; cf < 4; ++cf) {
                bf16x8 b = lds_frag(Bs, cf * 16 + (lane & 15), ks * 64 + ((lane >> 4) << 4));
                acc[cf] = mfma16(a, b, acc[cf]);
            }
        }
        __syncthreads();
    }

    // epilogue --------------------------------------------------------------
    const int sector = n0 >> 10;            // 0=q 1=k 2=v
    const int h = (n0 & 1023) >> 6;
    const float kc = hyp[h];

    float out[4][4];                        // [cf][r]
#pragma unroll
    for (int cf = 0; cf < 4; ++cf)
#pragma unroll
        for (int r = 0; r < 4; ++r) out[cf][r] = acc[cf][r];

    if (sector < 2) {
        // RoPE: pair (j, j+32) -> fragments (cf, cf+2), same lane.
#pragma unroll
        for (int cf = 0; cf < 2; ++cf) {
            const float j = (float)(cf * 16 + (lane & 15));
            const float invf = __expf(-0.28782313662425572f * j); // 10000^(-j/32)
#pragma unroll
            for (int r = 0; r < 4; ++r) {
                int m = m0 + wv * 16 + ((lane >> 4) << 2) + r;
                int t = m & (T_ - 1);
                float ang = (float)t * invf;
                float sn, cs; __sincosf(ang, &sn, &cs);
                float x1 = out[cf][r], x2 = out[cf + 2][r];
                out[cf][r]     =  x1 * cs + x2 * sn;
                out[cf + 2][r] = -x1 * sn + x2 * cs;
            }
        }
    }

#pragma unroll
    for (int r = 0; r < 4; ++r) {
        int m = m0 + wv * 16 + ((lane >> 4) << 2) + r;
        int b = m >> 10, t = m & (T_ - 1);
        int bh = b * H_ + h;
        size_t base = ((size_t)bh * T_ + t) * HD_;
        float nrm = 0.f;
#pragma unroll
        for (int cf = 0; cf < 4; ++cf) {
            int d = cf * 16 + (lane & 15);
            float v = out[cf][r];
            nrm += v * v;
            ushort bv = f2bf(v);
            if (sector == 0)      Qo[base + d] = bv;
            else if (sector == 1) Ko[base + d] = bv;
            else                  Vo[base + d] = bv;
        }
        if (sector < 2) {
#pragma unroll
            for (int mk = 1; mk < 16; mk <<= 1) nrm += __shfl_xor(nrm, mk);
            if ((lane & 15) == 0) {
                float v0 = sqrtf(kc + nrm);
                if (sector == 0) q0g[(size_t)bh * T_ + t] = v0;
                else             k0g[(size_t)bh * T_ + t] = v0;
            }
        }
    }
}

// ---------------------------------------------------------------------------
// Attention: one block = (b,h, 64 q-rows). 4 waves x 16 rows. Flash-style
// stream over 64-wide key tiles; QK^T + PV via bf16 MFMA; geometry fp32.
// ---------------------------------------------------------------------------
__global__ __launch_bounds__(256) void attn_fwd(
    const ushort* __restrict__ Q, const ushort* __restrict__ K, const ushort* __restrict__ V,
    const float* __restrict__ q0g, const float* __restrict__ k0g,
    const float* __restrict__ hyp, ushort* __restrict__ AO)
{
    __shared__ ushort Ks[64 * 64];
    __shared__ ushort Vts[64 * 64];       // V transposed: [d][s]
    __shared__ ushort Ps[4][16 * 64];     // per-wave P tile
    __shared__ float k0s[64];

    const int tid = threadIdx.x, lane = tid & 63, wv = tid >> 6;
    const int qt = blockIdx.x, bh = blockIdx.y;
    const int h = bh & (H_ - 1);
    const float kk = hyp[h];
    const float inv_k = __builtin_amdgcn_rcpf(kk);
    const float sqk = sqrtf(kk);

    // Q fragments live in registers for the whole kernel.
    const size_t qbase = ((size_t)bh * T_ + (size_t)qt * 64) * HD_;
    bf16x8 aq[2];
#pragma unroll
    for (int ks = 0; ks < 2; ++ks) {
        uint4 u = *(const uint4*)(Q + qbase + (size_t)(wv * 16 + (lane & 15)) * HD_
                                  + ks * 32 + ((lane >> 4) << 3));
        aq[ks] = __builtin_bit_cast(bf16x8, u);
    }
    float q0v[4];
#pragma unroll
    for (int r = 0; r < 4; ++r)
        q0v[r] = q0g[(size_t)bh * T_ + qt * 64 + wv * 16 + ((lane >> 4) << 2) + r];

    f32x4 oacc[4] = {};
    float mrun[4], lrun[4];
#pragma unroll
    for (int r = 0; r < 4; ++r) { mrun[r] = -1e30f; lrun[r] = 0.f; }

    for (int s0 = 0; s0 <= qt * 64; s0 += 64) {
        __syncthreads();  // previous iteration's LDS reads complete before restage
        stage_tile(Ks, K + ((size_t)bh * T_ + s0) * HD_, HD_, tid);
        {   // stage V transposed (coalesced global 8B loads, scattered b16 LDS writes)
            const ushort* vsrc = V + ((size_t)bh * T_ + s0) * HD_;
#pragma unroll
            for (int it = 0; it < 4; ++it) {
                int idx = tid + it * 256;          // 0..1023
                int s = idx >> 4, d0 = (idx & 15) * 4;
                ushort4 vvv = *(const ushort4*)(vsrc + (size_t)s * HD_ + d0);
                ushort el[4] = { vvv.x, vvv.y, vvv.z, vvv.w };
#pragma unroll
                for (int e = 0; e < 4; ++e) {
                    int d = d0 + e;
                    int addr = (d * 128 + s * 2) ^ ((d & 7) << 4);
                    *(ushort*)((char*)Vts + addr) = el[e];
                }
            }
        }
        if (tid < 64) k0s[tid] = k0g[(size_t)bh * T_ + s0 + tid];
        __syncthreads();

        // QK^T -> sc[sf] fragments (score rows = q-local (lane>>4)*4+r, cols sf*16+(lane&15))
        f32x4 sc[4] = {};
#pragma unroll
        for (int ks = 0; ks < 2; ++ks) {
#pragma unroll
            for (int sf = 0; sf < 4; ++sf) {
                bf16x8 bk = lds_frag(Ks, sf * 16 + (lane & 15), ks * 64 + ((lane >> 4) << 4));
                sc[sf] = mfma16(aq[ks], bk, sc[sf]);
            }
        }

        // hyperbolic geometry + online softmax (fp32)
        float pv[4][4]; // [sf][r] -> weight, then prob
        float mx[4];
#pragma unroll
        for (int r = 0; r < 4; ++r) {
            int qg = qt * 64 + wv * 16 + ((lane >> 4) << 2) + r;
            float rowmax = -1e30f;
#pragma unroll
            for (int sf = 0; sf < 4; ++sf) {
                int sl = sf * 16 + (lane & 15);
                int sg = s0 + sl;
                float inner = sc[sf][r] - q0v[r] * k0s[sl];
                float arg = fmaxf(-inner * inv_k, 1.0f + 1e-6f);
                float dis = sqk * __logf(arg + sqrtf(arg * arg - 1.0f));
                float wgt = __builtin_amdgcn_rcpf(1e-6f + dis);
                wgt = (sg <= qg) ? wgt : -1e30f;
                pv[sf][r] = wgt;
                rowmax = fmaxf(rowmax, wgt);
            }
#pragma unroll
            for (int mk = 1; mk < 16; mk <<= 1)
                rowmax = fmaxf(rowmax, __shfl_xor(rowmax, mk));
            mx[r] = rowmax;
        }
#pragma unroll
        for (int r = 0; r < 4; ++r) {
            float mnew = fmaxf(mrun[r], mx[r]);
            float scale = __expf(mrun[r] - mnew);
            mrun[r] = mnew;
            float rs = 0.f;
#pragma unroll
            for (int sf = 0; sf < 4; ++sf) {
                float p = __expf(pv[sf][r] - mnew);
                pv[sf][r] = p;
                rs += p;
            }
#pragma unroll
            for (int mk = 1; mk < 16; mk <<= 1) rs += __shfl_xor(rs, mk);
            lrun[r] = lrun[r] * scale + rs;
#pragma unroll
            for (int df = 0; df < 4; ++df) oacc[df][r] *= scale;
            // write P row to per-wave LDS (swizzled) for the PV A-operand
            int prow = ((lane >> 4) << 2) + r;
#pragma unroll
            for (int sf = 0; sf < 4; ++sf) {
                int col = sf * 16 + (lane & 15);
                int addr = (prow * 128 + col * 2) ^ ((prow & 7) << 4);
                *(ushort*)((char*)Ps[wv] + addr) = f2bf(pv[sf][r]);
            }
        }

        // PV: A = P (per-wave LDS), B = V^T tile
#pragma unroll
        for (int ks = 0; ks < 2; ++ks) {
            bf16x8 ap = lds_frag(Ps[wv], lane & 15, ks * 64 + ((lane >> 4) << 4));
#pragma unroll
            for (int df = 0; df < 4; ++df) {
                bf16x8 bv = lds_frag(Vts, df * 16 + (lane & 15), ks * 64 + ((lane >> 4) << 4));
                oacc[df] = mfma16(ap, bv, oacc[df]);
            }
        }
    }

    // epilogue: O /= l, scatter to (B,T,H*hd) bf16 for GEMM2
    const int b = bh >> 4;
#pragma unroll
    for (int r = 0; r < 4; ++r) {
        float inv_l = __builtin_amdgcn_rcpf(lrun[r]);
        int t = qt * 64 + wv * 16 + ((lane >> 4) << 2) + r;
        size_t base = ((size_t)b * T_ + t) * C_ + h * HD_;
#pragma unroll
        for (int df = 0; df < 4; ++df) {
            int d = df * 16 + (lane & 15);
            AO[base + d] = f2bf(oacc[df][r] * inv_l);
        }
    }
}

// ---------------------------------------------------------------------------
// GEMM2: out = attn @ W_out^T  -> fp32 d_out
// ---------------------------------------------------------------------------
__global__ __launch_bounds__(256) void gemm_out(
    const ushort* __restrict__ Ab, const ushort* __restrict__ Wb, float* __restrict__ Out)
{
    __shared__ ushort As[64 * 64];
    __shared__ ushort Bs[64 * 64];
    const int tid = threadIdx.x, lane = tid & 63, wv = tid >> 6;
    const int m0 = blockIdx.x * 64, n0 = blockIdx.y * 64;

    f32x4 acc[4] = {};
    for (int kt = 0; kt < C_ / 64; ++kt) {
        stage_tile(As, Ab + (size_t)m0 * C_ + kt * 64, C_, tid);
        stage_tile(Bs, Wb + (size_t)n0 * C_ + kt * 64, C_, tid);
        __syncthreads();
#pragma unroll
        for (int ks = 0; ks < 2; ++ks) {
            bf16x8 a = lds_frag(As, wv * 16 + (lane & 15), ks * 64 + ((lane >> 4) << 4));
#pragma unroll
            for (int cf = 0; cf < 4; ++cf) {
                bf16x8 b = lds_frag(Bs, cf * 16 + (lane & 15), ks * 64 + ((lane >> 4) << 4));
                acc[cf] = mfma16(a, b, acc[cf]);
            }
        }
        __syncthreads();
    }
#pragma unroll
    for (int cf = 0; cf < 4; ++cf)
#pragma unroll
        for (int r = 0; r < 4; ++r) {
            int m = m0 + wv * 16 + ((lane >> 4) << 2) + r;
            int n = n0 + cf * 16 + (lane & 15);
            Out[(size_t)m * C_ + n] = acc[cf][r];
        }
}

// ---------------------------------------------------------------------------
extern "C" void kernel_launch(void* const* d_in, const int* in_sizes, int n_in,
                              void* d_out, int out_size, void* d_ws, size_t ws_size,
                              hipStream_t stream)
{
    const float* x    = (const float*)d_in[0];
    const float* wqkv = (const float*)d_in[1];
    const float* wout = (const float*)d_in[2];
    const float* hyp  = (const float*)d_in[3];

    char* ws = (char*)d_ws;
    ushort* xb    = (ushort*)(ws + 0);
    ushort* wqkvb = (ushort*)(ws + 8388608);
    ushort* woutb = (ushort*)(ws + 14680064);
    ushort* Qb    = (ushort*)(ws + 16777216);
    ushort* Kb    = (ushort*)(ws + 25165824);
    ushort* Vb    = (ushort*)(ws + 33554432);
    ushort* Ab    = (ushort*)(ws + 41943040);
    float*  q0    = (float*)(ws + 50331648);
    float*  k0    = (float*)(ws + 50593792);

    cast_bf16<<<4096, 256, 0, stream>>>(x, xb, 4194304);
    cast_bf16<<<3072, 256, 0, stream>>>(wqkv, wqkvb, 3145728);
    cast_bf16<<<1024, 256, 0, stream>>>(wout, woutb, 1048576);

    gemm_qkv<<<dim3(64, 48), 256, 0, stream>>>(xb, wqkvb, hyp, Qb, Kb, Vb, q0, k0);
    attn_fwd<<<dim3(16, 64), 256, 0, stream>>>(Qb, Kb, Vb, q0, k0, hyp, Ab);
    gemm_out<<<dim3(64, 16), 256, 0, stream>>>(Ab, woutb, (float*)d_out);
}

// Round 2
// 143.234 us; speedup vs baseline: 1.5106x; 1.5106x over previous
//
#include <hip/hip_runtime.h>

#define B_ 4
#define T_ 1024
#define C_ 1024
#define H_ 16
#define HD_ 64

typedef short bf16x8 __attribute__((ext_vector_type(8)));
typedef float f32x4 __attribute__((ext_vector_type(4)));

__device__ __forceinline__ ushort f2bf(float f) {
    union { float f; unsigned u; } v; v.f = f;
    unsigned u = v.u;
    unsigned r = (u + 0x7fffu + ((u >> 16) & 1u)) >> 16;
    return (ushort)r;
}

__device__ __forceinline__ f32x4 mfma16(bf16x8 a, bf16x8 b, f32x4 c) {
    return __builtin_amdgcn_mfma_f32_16x16x32_bf16(a, b, c, 0, 0, 0);
}

// Read a 16B MFMA fragment from a [rows][64] ushort LDS tile (128B rows),
// XOR-swizzled: byte ^= (row&7)<<4.
__device__ __forceinline__ bf16x8 lds_frag(const ushort* base, int row, int byteoff) {
    int addr = (row * 128 + byteoff) ^ ((row & 7) << 4);
    uint4 u = *(const uint4*)((const char*)base + addr);
    return __builtin_bit_cast(bf16x8, u);
}

// V^T tile uses a two-term swizzle so BOTH the b32 transpose-writes and the
// b128 fragment reads are conflict-free: byte ^= (((d&7)^(d>>3))&7)<<4.
__device__ __forceinline__ bf16x8 lds_frag_v(const ushort* base, int d, int byteoff) {
    int addr = (d * 128 + byteoff) ^ ((((d & 7) ^ (d >> 3)) & 7) << 4);
    uint4 u = *(const uint4*)((const char*)base + addr);
    return __builtin_bit_cast(bf16x8, u);
}

// Stage a 64x64 ushort tile (global rows of `ld` elems) into swizzled LDS.
__device__ __forceinline__ void stage_tile(ushort* sdst, const ushort* gsrc, int ld, int tid) {
#pragma unroll
    for (int it = 0; it < 2; ++it) {
        int c = tid + it * 256;          // chunk 0..511
        int row = c >> 3, off = c & 7;   // 8 chunks per 128B row
        uint4 v = *(const uint4*)(gsrc + (size_t)row * ld + off * 8);
        int addr = (c * 16) ^ ((row & 7) << 4);
        *(uint4*)((char*)sdst + addr) = v;
    }
}

__global__ void cast_bf16(const float* __restrict__ in, ushort* __restrict__ out, int n) {
    int i = (blockIdx.x * 256 + threadIdx.x) * 4;
    if (i >= n) return;
    float4 v = *(const float4*)(in + i);
    ushort4 o = make_ushort4(f2bf(v.x), f2bf(v.y), f2bf(v.z), f2bf(v.w));
    *(ushort4*)(out + i) = o;
}

// ---------------------------------------------------------------------------
// GEMM1: qkv = x @ W_qkv^T (bf16 MFMA), fused RoPE + norms + scatter
// ---------------------------------------------------------------------------
__global__ __launch_bounds__(256) void gemm_qkv(
    const ushort* __restrict__ Xb, const ushort* __restrict__ Wb,
    const float* __restrict__ hyp,
    ushort* __restrict__ Qo, ushort* __restrict__ Ko, ushort* __restrict__ Vo,
    float* __restrict__ q0g, float* __restrict__ k0g)
{
    __shared__ ushort As[64 * 64];
    __shared__ ushort Bs[64 * 64];
    const int tid = threadIdx.x, lane = tid & 63, wv = tid >> 6;
    const int m0 = blockIdx.x * 64, n0 = blockIdx.y * 64;

    f32x4 acc[4] = {};
    for (int kt = 0; kt < C_ / 64; ++kt) {
        stage_tile(As, Xb + (size_t)m0 * C_ + kt * 64, C_, tid);
        stage_tile(Bs, Wb + (size_t)n0 * C_ + kt * 64, C_, tid);
        __syncthreads();
#pragma unroll
        for (int ks = 0; ks < 2; ++ks) {
            bf16x8 a = lds_frag(As, wv * 16 + (lane & 15), ks * 64 + ((lane >> 4) << 4));
#pragma unroll
            for (int cf = 0; cf < 4; ++cf) {
                bf16x8 b = lds_frag(Bs, cf * 16 + (lane & 15), ks * 64 + ((lane >> 4) << 4));
                acc[cf] = mfma16(a, b, acc[cf]);
            }
        }
        __syncthreads();
    }

    const int sector = n0 >> 10;            // 0=q 1=k 2=v
    const int h = (n0 & 1023) >> 6;
    const float kc = hyp[h];

    float out[4][4];
#pragma unroll
    for (int cf = 0; cf < 4; ++cf)
#pragma unroll
        for (int r = 0; r < 4; ++r) out[cf][r] = acc[cf][r];

    if (sector < 2) {
#pragma unroll
        for (int cf = 0; cf < 2; ++cf) {
            const float j = (float)(cf * 16 + (lane & 15));
            const float invf = __expf(-0.28782313662425572f * j); // 10000^(-j/32)
#pragma unroll
            for (int r = 0; r < 4; ++r) {
                int m = m0 + wv * 16 + ((lane >> 4) << 2) + r;
                int t = m & (T_ - 1);
                float ang = (float)t * invf;
                float sn, cs; __sincosf(ang, &sn, &cs);
                float x1 = out[cf][r], x2 = out[cf + 2][r];
                out[cf][r]     =  x1 * cs + x2 * sn;
                out[cf + 2][r] = -x1 * sn + x2 * cs;
            }
        }
    }

#pragma unroll
    for (int r = 0; r < 4; ++r) {
        int m = m0 + wv * 16 + ((lane >> 4) << 2) + r;
        int b = m >> 10, t = m & (T_ - 1);
        int bh = b * H_ + h;
        size_t base = ((size_t)bh * T_ + t) * HD_;
        float nrm = 0.f;
#pragma unroll
        for (int cf = 0; cf < 4; ++cf) {
            int d = cf * 16 + (lane & 15);
            float v = out[cf][r];
            nrm += v * v;
            ushort bv = f2bf(v);
            if (sector == 0)      Qo[base + d] = bv;
            else if (sector == 1) Ko[base + d] = bv;
            else                  Vo[base + d] = bv;
        }
        if (sector < 2) {
#pragma unroll
            for (int mk = 1; mk < 16; mk <<= 1) nrm += __shfl_xor(nrm, mk);
            if ((lane & 15) == 0) {
                float v0 = sqrtf(kc + nrm);
                if (sector == 0) q0g[(size_t)bh * T_ + t] = v0;
                else             k0g[(size_t)bh * T_ + t] = v0;
            }
        }
    }
}

// ---------------------------------------------------------------------------
// Attention. Grid: 1024 1D blocks, bid -> qt = 15 - bid/64 (longest first),
// bh = bid&63 (same bh at stride 64 -> same XCD -> K/V L2 reuse).
// Double-buffered: next tile's K/V/k0 global loads are issued into registers
// while the current tile computes; regs -> LDS after the barrier.
// ---------------------------------------------------------------------------
__global__ __launch_bounds__(256) void attn_fwd(
    const ushort* __restrict__ Q, const ushort* __restrict__ K, const ushort* __restrict__ V,
    const float* __restrict__ q0g, const float* __restrict__ k0g,
    const float* __restrict__ hyp, ushort* __restrict__ AO)
{
    __shared__ ushort Ks[64 * 64];
    __shared__ ushort Vts[64 * 64];       // [d][s-pair] uint-packed, v-swizzled
    __shared__ ushort Ps[4][16 * 64];     // per-wave P tile
    __shared__ float k0s[64];

    const int tid = threadIdx.x, lane = tid & 63, wv = tid >> 6;
    const int bid = blockIdx.x;
    const int qt = 15 - (bid >> 6);
    const int bh = bid & 63;
    const int h = bh & (H_ - 1);
    const float kk = hyp[h];
    const float inv_k = __builtin_amdgcn_rcpf(kk);
    const float sqk = sqrtf(kk);
    const int nt = qt + 1;

    const ushort* Kb = K + (size_t)bh * T_ * HD_;
    const ushort* Vb = V + (size_t)bh * T_ * HD_;

    // Q fragments in registers for the whole kernel
    const size_t qbase = ((size_t)bh * T_ + (size_t)qt * 64) * HD_;
    bf16x8 aq[2];
#pragma unroll
    for (int ks = 0; ks < 2; ++ks) {
        uint4 u = *(const uint4*)(Q + qbase + (size_t)(wv * 16 + (lane & 15)) * HD_
                                  + ks * 32 + ((lane >> 4) << 3));
        aq[ks] = __builtin_bit_cast(bf16x8, u);
    }
    float q0v[4];
#pragma unroll
    for (int r = 0; r < 4; ++r)
        q0v[r] = q0g[(size_t)bh * T_ + qt * 64 + wv * 16 + ((lane >> 4) << 2) + r];

    f32x4 oacc[4] = {};
    float mrun[4], lrun[4];
#pragma unroll
    for (int r = 0; r < 4; ++r) { mrun[r] = -1e30f; lrun[r] = 0.f; }

    // staging register state ------------------------------------------------
    const int krow = tid >> 3, koff = tid & 7;       // K chunks: tid and tid+256
    const int sp = tid >> 3, dc = tid & 7;           // V: s-pair, d-chunk
    uint4 kv0, kv1, vv0, vv1;
    float kz = 0.f;

    auto issue = [&](int s0) {
        kv0 = *(const uint4*)(Kb + (size_t)(s0 + krow) * HD_ + koff * 8);
        kv1 = *(const uint4*)(Kb + (size_t)(s0 + 32 + krow) * HD_ + koff * 8);
        vv0 = *(const uint4*)(Vb + (size_t)(s0 + 2 * sp) * HD_ + dc * 8);
        vv1 = *(const uint4*)(Vb + (size_t)(s0 + 2 * sp + 1) * HD_ + dc * 8);
        if (tid < 64) kz = k0g[(size_t)bh * T_ + s0 + tid];
    };

    issue(0);

    for (int it = 0; it < nt; ++it) {
        const int s0 = it * 64;
        const bool diag = (it == nt - 1);

        __syncthreads();   // all waves done reading LDS from previous tile
        {   // K: two b128 writes (chunks tid, tid+256)
            int c0 = tid, c1 = tid + 256;
            *(uint4*)((char*)Ks + ((c0 * 16) ^ ((krow & 7) << 4))) = kv0;
            *(uint4*)((char*)Ks + ((c1 * 16) ^ (((c1 >> 3) & 7) << 4))) = kv1;
            // V transpose: pack s-pairs into b32, conflict-free swizzle
            union { uint4 v; ushort u[8]; } a, b;
            a.v = vv0; b.v = vv1;
#pragma unroll
            for (int j = 0; j < 8; ++j) {
                int d = dc * 8 + j;
                uint pack = (uint)a.u[j] | ((uint)b.u[j] << 16);
                int addr = (d * 128 + sp * 4) ^ (((j ^ dc) & 7) << 4);
                *(uint*)((char*)Vts + addr) = pack;
            }
            if (tid < 64) k0s[tid] = kz;
        }
        if (it + 1 < nt) issue(s0 + 64);   // prefetch next tile (in flight during compute)
        __syncthreads();   // LDS ready

        // QK^T
        f32x4 sc[4] = {};
#pragma unroll
        for (int ks = 0; ks < 2; ++ks) {
#pragma unroll
            for (int sf = 0; sf < 4; ++sf) {
                bf16x8 bk = lds_frag(Ks, sf * 16 + (lane & 15), ks * 64 + ((lane >> 4) << 4));
                sc[sf] = mfma16(aq[ks], bk, sc[sf]);
            }
        }

        // hyperbolic geometry (fp32)
        float pvv[4][4];
#pragma unroll
        for (int r = 0; r < 4; ++r) {
#pragma unroll
            for (int sf = 0; sf < 4; ++sf) {
                int sl = sf * 16 + (lane & 15);
                float inner = sc[sf][r] - q0v[r] * k0s[sl];
                float arg = fmaxf(-inner * inv_k, 1.0f + 1e-6f);
                float dis = sqk * __logf(arg + sqrtf(arg * arg - 1.0f));
                pvv[sf][r] = __builtin_amdgcn_rcpf(1e-6f + dis);
            }
        }
        if (diag) {    // causal mask only on the diagonal tile
            const int qloc = wv * 16 + ((lane >> 4) << 2);
#pragma unroll
            for (int r = 0; r < 4; ++r)
#pragma unroll
                for (int sf = 0; sf < 4; ++sf) {
                    int sl = sf * 16 + (lane & 15);
                    if (sl > qloc + r) pvv[sf][r] = -1e30f;
                }
        }

        // online softmax + P write
#pragma unroll
        for (int r = 0; r < 4; ++r) {
            float rowmax = fmaxf(fmaxf(pvv[0][r], pvv[1][r]), fmaxf(pvv[2][r], pvv[3][r]));
#pragma unroll
            for (int mk = 1; mk < 16; mk <<= 1)
                rowmax = fmaxf(rowmax, __shfl_xor(rowmax, mk));
            float mnew = fmaxf(mrun[r], rowmax);
            float scale = __expf(mrun[r] - mnew);
            mrun[r] = mnew;
            float rs = 0.f;
#pragma unroll
            for (int sf = 0; sf < 4; ++sf) {
                float p = __expf(pvv[sf][r] - mnew);
                pvv[sf][r] = p;
                rs += p;
            }
#pragma unroll
            for (int mk = 1; mk < 16; mk <<= 1) rs += __shfl_xor(rs, mk);
            lrun[r] = lrun[r] * scale + rs;
#pragma unroll
            for (int df = 0; df < 4; ++df) oacc[df][r] *= scale;
            int prow = ((lane >> 4) << 2) + r;
#pragma unroll
            for (int sf = 0; sf < 4; ++sf) {
                int col = sf * 16 + (lane & 15);
                int addr = (prow * 128 + col * 2) ^ ((prow & 7) << 4);
                *(ushort*)((char*)Ps[wv] + addr) = f2bf(pvv[sf][r]);
            }
        }

        // PV
#pragma unroll
        for (int ks = 0; ks < 2; ++ks) {
            bf16x8 ap = lds_frag(Ps[wv], lane & 15, ks * 64 + ((lane >> 4) << 4));
#pragma unroll
            for (int df = 0; df < 4; ++df) {
                bf16x8 bv = lds_frag_v(Vts, df * 16 + (lane & 15), ks * 64 + ((lane >> 4) << 4));
                oacc[df] = mfma16(ap, bv, oacc[df]);
            }
        }
    }

    // epilogue
    const int b = bh >> 4;
#pragma unroll
    for (int r = 0; r < 4; ++r) {
        float inv_l = __builtin_amdgcn_rcpf(lrun[r]);
        int t = qt * 64 + wv * 16 + ((lane >> 4) << 2) + r;
        size_t base = ((size_t)b * T_ + t) * C_ + h * HD_;
#pragma unroll
        for (int df = 0; df < 4; ++df) {
            int d = df * 16 + (lane & 15);
            AO[base + d] = f2bf(oacc[df][r] * inv_l);
        }
    }
}

// ---------------------------------------------------------------------------
// GEMM2: out = attn @ W_out^T -> fp32
// ---------------------------------------------------------------------------
__global__ __launch_bounds__(256) void gemm_out(
    const ushort* __restrict__ Ab, const ushort* __restrict__ Wb, float* __restrict__ Out)
{
    __shared__ ushort As[64 * 64];
    __shared__ ushort Bs[64 * 64];
    const int tid = threadIdx.x, lane = tid & 63, wv = tid >> 6;
    const int m0 = blockIdx.x * 64, n0 = blockIdx.y * 64;

    f32x4 acc[4] = {};
    for (int kt = 0; kt < C_ / 64; ++kt) {
        stage_tile(As, Ab + (size_t)m0 * C_ + kt * 64, C_, tid);
        stage_tile(Bs, Wb + (size_t)n0 * C_ + kt * 64, C_, tid);
        __syncthreads();
#pragma unroll
        for (int ks = 0; ks < 2; ++ks) {
            bf16x8 a = lds_frag(As, wv * 16 + (lane & 15), ks * 64 + ((lane >> 4) << 4));
#pragma unroll
            for (int cf = 0; cf < 4; ++cf) {
                bf16x8 b = lds_frag(Bs, cf * 16 + (lane & 15), ks * 64 + ((lane >> 4) << 4));
                acc[cf] = mfma16(a, b, acc[cf]);
            }
        }
        __syncthreads();
    }
#pragma unroll
    for (int cf = 0; cf < 4; ++cf)
#pragma unroll
        for (int r = 0; r < 4; ++r) {
            int m = m0 + wv * 16 + ((lane >> 4) << 2) + r;
            int n = n0 + cf * 16 + (lane & 15);
            Out[(size_t)m * C_ + n] = acc[cf][r];
        }
}

// ---------------------------------------------------------------------------
extern "C" void kernel_launch(void* const* d_in, const int* in_sizes, int n_in,
                              void* d_out, int out_size, void* d_ws, size_t ws_size,
                              hipStream_t stream)
{
    const float* x    = (const float*)d_in[0];
    const float* wqkv = (const float*)d_in[1];
    const float* wout = (const float*)d_in[2];
    const float* hyp  = (const float*)d_in[3];

    char* ws = (char*)d_ws;
    ushort* xb    = (ushort*)(ws + 0);
    ushort* wqkvb = (ushort*)(ws + 8388608);
    ushort* woutb = (ushort*)(ws + 14680064);
    ushort* Qb    = (ushort*)(ws + 16777216);
    ushort* Kb    = (ushort*)(ws + 25165824);
    ushort* Vb    = (ushort*)(ws + 33554432);
    ushort* Ab    = (ushort*)(ws + 41943040);
    float*  q0    = (float*)(ws + 50331648);
    float*  k0    = (float*)(ws + 50593792);

    cast_bf16<<<4096, 256, 0, stream>>>(x, xb, 4194304);
    cast_bf16<<<3072, 256, 0, stream>>>(wqkv, wqkvb, 3145728);
    cast_bf16<<<1024, 256, 0, stream>>>(wout, woutb, 1048576);

    gemm_qkv<<<dim3(64, 48), 256, 0, stream>>>(xb, wqkvb, hyp, Qb, Kb, Vb, q0, k0);
    attn_fwd<<<1024, 256, 0, stream>>>(Qb, Kb, Vb, q0, k0, hyp, Ab);
    gemm_out<<<dim3(64, 16), 256, 0, stream>>>(Ab, woutb, (float*)d_out);
}

// Round 3
// 108.996 us; speedup vs baseline: 1.9852x; 1.3141x over previous
//
#include <hip/hip_runtime.h>

#define B_ 4
#define T_ 1024
#define C_ 1024
#define H_ 16
#define HD_ 64

typedef short bf16x8 __attribute__((ext_vector_type(8)));
typedef float f32x4 __attribute__((ext_vector_type(4)));

__device__ __forceinline__ ushort f2bf(float f) {
    union { float f; unsigned u; } v; v.f = f;
    unsigned u = v.u;
    unsigned r = (u + 0x7fffu + ((u >> 16) & 1u)) >> 16;
    return (ushort)r;
}

__device__ __forceinline__ f32x4 mfma16(bf16x8 a, bf16x8 b, f32x4 c) {
    return __builtin_amdgcn_mfma_f32_16x16x32_bf16(a, b, c, 0, 0, 0);
}

// [rows][64] ushort tile, swizzle byte ^= (row&7)<<4 (K/A/B tiles).
__device__ __forceinline__ bf16x8 lds_frag(const ushort* base, int row, int byteoff) {
    int addr = (row * 128 + byteoff) ^ ((row & 7) << 4);
    uint4 u = *(const uint4*)((const char*)base + addr);
    return __builtin_bit_cast(bf16x8, u);
}

// V^T tile: byte ^= (((d&7)^(d>>3))&7)<<4 (b32 transpose-writes + b128 reads both clean).
__device__ __forceinline__ bf16x8 lds_frag_v(const ushort* base, int d, int byteoff) {
    int addr = (d * 128 + byteoff) ^ ((((d & 7) ^ (d >> 3)) & 7) << 4);
    uint4 u = *(const uint4*)((const char*)base + addr);
    return __builtin_bit_cast(bf16x8, u);
}

// P tile (16 rows): swizzle ((row>>2)&3)<<5 -> the 4 written row-groups
// {r,r+4,r+8,r+12} land in 4 disjoint bank octets (conflict-free b16 writes),
// and the b128 read is uniform 8 dwords/bank.
__device__ __forceinline__ bf16x8 lds_frag_p(const ushort* base, int row, int byteoff) {
    int addr = (row * 128 + byteoff) ^ (((row >> 2) & 3) << 5);
    uint4 u = *(const uint4*)((const char*)base + addr);
    return __builtin_bit_cast(bf16x8, u);
}

__device__ __forceinline__ void stage_tile(ushort* sdst, const ushort* gsrc, int ld, int tid) {
#pragma unroll
    for (int it = 0; it < 2; ++it) {
        int c = tid + it * 256;
        int row = c >> 3, off = c & 7;
        uint4 v = *(const uint4*)(gsrc + (size_t)row * ld + off * 8);
        int addr = (c * 16) ^ ((row & 7) << 4);
        *(uint4*)((char*)sdst + addr) = v;
    }
}

__global__ void cast_bf16(const float* __restrict__ in, ushort* __restrict__ out, int n) {
    int i = (blockIdx.x * 256 + threadIdx.x) * 4;
    if (i >= n) return;
    float4 v = *(const float4*)(in + i);
    ushort4 o = make_ushort4(f2bf(v.x), f2bf(v.y), f2bf(v.z), f2bf(v.w));
    *(ushort4*)(out + i) = o;
}

// ---------------------------------------------------------------------------
// GEMM1: qkv = x @ W_qkv^T (bf16 MFMA), fused RoPE + norms + kappa-prescale.
// K is stored as K/kappa and k0 as k0/kappa so attention's arg is one fma.
// ---------------------------------------------------------------------------
__global__ __launch_bounds__(256) void gemm_qkv(
    const ushort* __restrict__ Xb, const ushort* __restrict__ Wb,
    const float* __restrict__ hyp,
    ushort* __restrict__ Qo, ushort* __restrict__ Ko, ushort* __restrict__ Vo,
    float* __restrict__ q0g, float* __restrict__ k0g)
{
    __shared__ ushort As[64 * 64];
    __shared__ ushort Bs[64 * 64];
    const int tid = threadIdx.x, lane = tid & 63, wv = tid >> 6;
    const int m0 = blockIdx.x * 64, n0 = blockIdx.y * 64;

    f32x4 acc[4] = {};
    for (int kt = 0; kt < C_ / 64; ++kt) {
        stage_tile(As, Xb + (size_t)m0 * C_ + kt * 64, C_, tid);
        stage_tile(Bs, Wb + (size_t)n0 * C_ + kt * 64, C_, tid);
        __syncthreads();
#pragma unroll
        for (int ks = 0; ks < 2; ++ks) {
            bf16x8 a = lds_frag(As, wv * 16 + (lane & 15), ks * 64 + ((lane >> 4) << 4));
#pragma unroll
            for (int cf = 0; cf < 4; ++cf) {
                bf16x8 b = lds_frag(Bs, cf * 16 + (lane & 15), ks * 64 + ((lane >> 4) << 4));
                acc[cf] = mfma16(a, b, acc[cf]);
            }
        }
        __syncthreads();
    }

    const int sector = n0 >> 10;            // 0=q 1=k 2=v
    const int h = (n0 & 1023) >> 6;
    const float kc = hyp[h];
    const float inv_k = 1.0f / kc;

    float out[4][4];
#pragma unroll
    for (int cf = 0; cf < 4; ++cf)
#pragma unroll
        for (int r = 0; r < 4; ++r) out[cf][r] = acc[cf][r];

    if (sector < 2) {
#pragma unroll
        for (int cf = 0; cf < 2; ++cf) {
            const float j = (float)(cf * 16 + (lane & 15));
            const float invf = __expf(-0.28782313662425572f * j); // 10000^(-j/32)
#pragma unroll
            for (int r = 0; r < 4; ++r) {
                int m = m0 + wv * 16 + ((lane >> 4) << 2) + r;
                int t = m & (T_ - 1);
                float ang = (float)t * invf;
                float sn, cs; __sincosf(ang, &sn, &cs);
                float x1 = out[cf][r], x2 = out[cf + 2][r];
                out[cf][r]     =  x1 * cs + x2 * sn;
                out[cf + 2][r] = -x1 * sn + x2 * cs;
            }
        }
    }

#pragma unroll
    for (int r = 0; r < 4; ++r) {
        int m = m0 + wv * 16 + ((lane >> 4) << 2) + r;
        int b = m >> 10, t = m & (T_ - 1);
        int bh = b * H_ + h;
        size_t base = ((size_t)bh * T_ + t) * HD_;
        float nrm = 0.f;
#pragma unroll
        for (int cf = 0; cf < 4; ++cf) {
            int d = cf * 16 + (lane & 15);
            float v = out[cf][r];
            nrm += v * v;
            ushort bv = f2bf(sector == 1 ? v * inv_k : v);
            if (sector == 0)      Qo[base + d] = bv;
            else if (sector == 1) Ko[base + d] = bv;
            else                  Vo[base + d] = bv;
        }
        if (sector < 2) {
#pragma unroll
            for (int mk = 1; mk < 16; mk <<= 1) nrm += __shfl_xor(nrm, mk);
            if ((lane & 15) == 0) {
                float v0 = sqrtf(kc + nrm);
                if (sector == 0) q0g[(size_t)bh * T_ + t] = v0;
                else             k0g[(size_t)bh * T_ + t] = v0 * inv_k;
            }
        }
    }
}

// ---------------------------------------------------------------------------
// Attention, paired q-tiles for load balance: block (p, bh) handles q-tiles
// qa=p and qb=15-p sharing one K/V stream => every block = 17 compute-tiles.
// Fixed-max softmax (weights bounded <=~3): no rowmax, no rescale; row-sum
// deferred to epilogue. K/k0 arrive pre-divided by kappa.
// ---------------------------------------------------------------------------
__global__ __launch_bounds__(256, 2) void attn_fwd(
    const ushort* __restrict__ Q, const ushort* __restrict__ K, const ushort* __restrict__ V,
    const float* __restrict__ q0g, const float* __restrict__ k0g,
    const float* __restrict__ hyp, ushort* __restrict__ AO)
{
    __shared__ ushort Ks[64 * 64];
    __shared__ ushort Vts[64 * 64];
    __shared__ ushort Ps[8][16 * 64];     // [wv*2 + (0=A,1=B)]
    __shared__ float k0s[64];

    const int tid = threadIdx.x, lane = tid & 63, wv = tid >> 6;
    const int pr = blockIdx.x >> 6;       // 0..7
    const int bh = blockIdx.x & 63;
    const int h = bh & (H_ - 1);
    const int qa = pr, qb = 15 - pr, nt = qb + 1;
    const float c3 = sqrtf(hyp[h]) * 0.48045301391820142f;  // sqrt(k)*ln2^2
    const float e3 = 6.931471805599453e-07f;                // 1e-6*ln2

    const ushort* Kb = K + (size_t)bh * T_ * HD_;
    const ushort* Vb = V + (size_t)bh * T_ * HD_;

    bf16x8 aqA[2], aqB[2];
    {
        const ushort* qA = Q + ((size_t)bh * T_ + qa * 64 + wv * 16 + (lane & 15)) * HD_;
        const ushort* qB = Q + ((size_t)bh * T_ + qb * 64 + wv * 16 + (lane & 15)) * HD_;
#pragma unroll
        for (int ks = 0; ks < 2; ++ks) {
            aqA[ks] = __builtin_bit_cast(bf16x8, *(const uint4*)(qA + ks * 32 + ((lane >> 4) << 3)));
            aqB[ks] = __builtin_bit_cast(bf16x8, *(const uint4*)(qB + ks * 32 + ((lane >> 4) << 3)));
        }
    }
    float q0A[4], q0B[4];
#pragma unroll
    for (int r = 0; r < 4; ++r) {
        int rr = wv * 16 + ((lane >> 4) << 2) + r;
        q0A[r] = q0g[(size_t)bh * T_ + qa * 64 + rr];
        q0B[r] = q0g[(size_t)bh * T_ + qb * 64 + rr];
    }

    f32x4 oaccA[4] = {}, oaccB[4] = {};
    float lpA[4] = {}, lpB[4] = {};

    const int krow = tid >> 3, koff = tid & 7;
    const int sp = tid >> 3, dc = tid & 7;
    uint4 kv0, kv1, vv0, vv1;
    float kz = 0.f;
    auto issue = [&](int s0) {
        kv0 = *(const uint4*)(Kb + (size_t)(s0 + krow) * HD_ + koff * 8);
        kv1 = *(const uint4*)(Kb + (size_t)(s0 + 32 + krow) * HD_ + koff * 8);
        vv0 = *(const uint4*)(Vb + (size_t)(s0 + 2 * sp) * HD_ + dc * 8);
        vv1 = *(const uint4*)(Vb + (size_t)(s0 + 2 * sp + 1) * HD_ + dc * 8);
        if (tid < 64) kz = k0g[(size_t)bh * T_ + s0 + tid];
    };

    auto geom = [&](const f32x4* sc, const float* q0, const float* k0r, float p[4][4]) {
#pragma unroll
        for (int r = 0; r < 4; ++r)
#pragma unroll
            for (int sf = 0; sf < 4; ++sf) {
                float arg = fmaf(q0[r], k0r[sf], -sc[sf][r]);   // (q0k0 - qk)/kappa
                arg = fmaxf(arg, 1.0f + 1e-6f);
                float t = fmaf(arg, arg, -1.0f);
                float u = arg + __builtin_amdgcn_sqrtf(t);
                float l2 = __builtin_amdgcn_logf(u);            // log2(u)
                float w2 = fmaf(l2, c3, e3);                    // ln2*(eps + dis)
                float rv = fminf(__builtin_amdgcn_rcpf(w2), 30.0f); // log2(e^wgt)
                p[sf][r] = __builtin_amdgcn_exp2f(rv);
            }
    };
    auto mask_diag = [&](float p[4][4]) {
        const int qloc = wv * 16 + ((lane >> 4) << 2);
#pragma unroll
        for (int r = 0; r < 4; ++r)
#pragma unroll
            for (int sf = 0; sf < 4; ++sf)
                if (sf * 16 + (lane & 15) > qloc + r) p[sf][r] = 0.f;
    };
    auto pv_step = [&](float p[4][4], ushort* ps, const bf16x8 (&vf)[2][4],
                       f32x4* oacc, float* lp) {
#pragma unroll
        for (int r = 0; r < 4; ++r) {
            int row = ((lane >> 4) << 2) + r;
#pragma unroll
            for (int sf = 0; sf < 4; ++sf) {
                int addr = (row * 128 + (sf * 16 + (lane & 15)) * 2) ^ (((row >> 2) & 3) << 5);
                *(ushort*)((char*)ps + addr) = f2bf(p[sf][r]);
            }
            lp[r] += (p[0][r] + p[1][r]) + (p[2][r] + p[3][r]);
        }
#pragma unroll
        for (int ks = 0; ks < 2; ++ks) {
            bf16x8 ap = lds_frag_p(ps, lane & 15, ks * 64 + ((lane >> 4) << 4));
#pragma unroll
            for (int df = 0; df < 4; ++df)
                oacc[df] = mfma16(ap, vf[ks][df], oacc[df]);
        }
    };

    issue(0);

    for (int it = 0; it < nt; ++it) {
        const bool actA = (it <= qa);
        __syncthreads();
        {
            *(uint4*)((char*)Ks + ((tid * 16) ^ ((krow & 7) << 4))) = kv0;
            int c1 = tid + 256;
            *(uint4*)((char*)Ks + ((c1 * 16) ^ (((c1 >> 3) & 7) << 4))) = kv1;
            union { uint4 v; ushort u[8]; } a, b;
            a.v = vv0; b.v = vv1;
#pragma unroll
            for (int j = 0; j < 8; ++j) {
                int d = dc * 8 + j;
                uint pack = (uint)a.u[j] | ((uint)b.u[j] << 16);
                *(uint*)((char*)Vts + ((d * 128 + sp * 4) ^ (((j ^ dc) & 7) << 4))) = pack;
            }
            if (tid < 64) k0s[tid] = kz;
        }
        if (it + 1 < nt) issue((it + 1) * 64);
        __syncthreads();

        bf16x8 bk[2][4];
#pragma unroll
        for (int ks = 0; ks < 2; ++ks)
#pragma unroll
            for (int sf = 0; sf < 4; ++sf)
                bk[ks][sf] = lds_frag(Ks, sf * 16 + (lane & 15), ks * 64 + ((lane >> 4) << 4));

        float k0r[4];
#pragma unroll
        for (int sf = 0; sf < 4; ++sf) k0r[sf] = k0s[sf * 16 + (lane & 15)];

        f32x4 scB[4] = {};
#pragma unroll
        for (int ks = 0; ks < 2; ++ks)
#pragma unroll
            for (int sf = 0; sf < 4; ++sf)
                scB[sf] = mfma16(aqB[ks], bk[ks][sf], scB[sf]);
        f32x4 scA[4] = {};
        if (actA) {
#pragma unroll
            for (int ks = 0; ks < 2; ++ks)
#pragma unroll
                for (int sf = 0; sf < 4; ++sf)
                    scA[sf] = mfma16(aqA[ks], bk[ks][sf], scA[sf]);
        }

        bf16x8 vf[2][4];
#pragma unroll
        for (int ks = 0; ks < 2; ++ks)
#pragma unroll
            for (int df = 0; df < 4; ++df)
                vf[ks][df] = lds_frag_v(Vts, df * 16 + (lane & 15), ks * 64 + ((lane >> 4) << 4));

        float pB[4][4];
        geom(scB, q0B, k0r, pB);
        if (it == qb) mask_diag(pB);
        pv_step(pB, Ps[wv * 2 + 1], vf, oaccB, lpB);

        if (actA) {
            float pA[4][4];
            geom(scA, q0A, k0r, pA);
            if (it == qa) mask_diag(pA);
            pv_step(pA, Ps[wv * 2 + 0], vf, oaccA, lpA);
        }
    }

    const int b = bh >> 4;
    auto epi = [&](f32x4* oacc, float* lp, int qt) {
#pragma unroll
        for (int r = 0; r < 4; ++r) {
            float s = lp[r];
#pragma unroll
            for (int mk = 1; mk < 16; mk <<= 1) s += __shfl_xor(s, mk);
            float invl = __builtin_amdgcn_rcpf(s);
            int t = qt * 64 + wv * 16 + ((lane >> 4) << 2) + r;
            size_t base = ((size_t)b * T_ + t) * C_ + h * HD_;
#pragma unroll
            for (int df = 0; df < 4; ++df)
                AO[base + df * 16 + (lane & 15)] = f2bf(oacc[df][r] * invl);
        }
    };
    epi(oaccA, lpA, qa);
    epi(oaccB, lpB, qb);
}

// ---------------------------------------------------------------------------
// GEMM2: out = attn @ W_out^T -> fp32
// ---------------------------------------------------------------------------
__global__ __launch_bounds__(256) void gemm_out(
    const ushort* __restrict__ Ab, const ushort* __restrict__ Wb, float* __restrict__ Out)
{
    __shared__ ushort As[64 * 64];
    __shared__ ushort Bs[64 * 64];
    const int tid = threadIdx.x, lane = tid & 63, wv = tid >> 6;
    const int m0 = blockIdx.x * 64, n0 = blockIdx.y * 64;

    f32x4 acc[4] = {};
    for (int kt = 0; kt < C_ / 64; ++kt) {
        stage_tile(As, Ab + (size_t)m0 * C_ + kt * 64, C_, tid);
        stage_tile(Bs, Wb + (size_t)n0 * C_ + kt * 64, C_, tid);
        __syncthreads();
#pragma unroll
        for (int ks = 0; ks < 2; ++ks) {
            bf16x8 a = lds_frag(As, wv * 16 + (lane & 15), ks * 64 + ((lane >> 4) << 4));
#pragma unroll
            for (int cf = 0; cf < 4; ++cf) {
                bf16x8 b = lds_frag(Bs, cf * 16 + (lane & 15), ks * 64 + ((lane >> 4) << 4));
                acc[cf] = mfma16(a, b, acc[cf]);
            }
        }
        __syncthreads();
    }
#pragma unroll
    for (int cf = 0; cf < 4; ++cf)
#pragma unroll
        for (int r = 0; r < 4; ++r) {
            int m = m0 + wv * 16 + ((lane >> 4) << 2) + r;
            int n = n0 + cf * 16 + (lane & 15);
            Out[(size_t)m * C_ + n] = acc[cf][r];
        }
}

// ---------------------------------------------------------------------------
extern "C" void kernel_launch(void* const* d_in, const int* in_sizes, int n_in,
                              void* d_out, int out_size, void* d_ws, size_t ws_size,
                              hipStream_t stream)
{
    const float* x    = (const float*)d_in[0];
    const float* wqkv = (const float*)d_in[1];
    const float* wout = (const float*)d_in[2];
    const float* hyp  = (const float*)d_in[3];

    char* ws = (char*)d_ws;
    ushort* xb    = (ushort*)(ws + 0);
    ushort* wqkvb = (ushort*)(ws + 8388608);
    ushort* woutb = (ushort*)(ws + 14680064);
    ushort* Qb    = (ushort*)(ws + 16777216);
    ushort* Kb    = (ushort*)(ws + 25165824);
    ushort* Vb    = (ushort*)(ws + 33554432);
    ushort* Ab    = (ushort*)(ws + 41943040);
    float*  q0    = (float*)(ws + 50331648);
    float*  k0    = (float*)(ws + 50593792);

    cast_bf16<<<4096, 256, 0, stream>>>(x, xb, 4194304);
    cast_bf16<<<3072, 256, 0, stream>>>(wqkv, wqkvb, 3145728);
    cast_bf16<<<1024, 256, 0, stream>>>(wout, woutb, 1048576);

    gemm_qkv<<<dim3(64, 48), 256, 0, stream>>>(xb, wqkvb, hyp, Qb, Kb, Vb, q0, k0);
    attn_fwd<<<512, 256, 0, stream>>>(Qb, Kb, Vb, q0, k0, hyp, Ab);
    gemm_out<<<dim3(64, 16), 256, 0, stream>>>(Ab, woutb, (float*)d_out);
}